// Round 1
// baseline (1844.488 us; speedup 1.0000x reference)
//
#include <hip/hip_runtime.h>
#include <hip/hip_bf16.h>

#define B_ 256
#define T_ 32
#define F_ 128
#define H_ 128
#define NF 64
#define OH 31
#define OW 255
#define KFLAT (NF*OH*OW)   // 505920
#define N1 256

// ---------------- K1: attention -> feat (B,32,256) ----------------
__global__ __launch_bounds__(256) void k_attn(
    const float* __restrict__ X, const float* __restrict__ W,
    const float* __restrict__ U, const float* __restrict__ V,
    float* __restrict__ feat)
{
    __shared__ float Xs[T_][F_];
    __shared__ float xw[T_][H_];
    __shared__ float xu[T_][H_];
    __shared__ float sc[T_][T_];
    __shared__ float Vs[H_];

    const int b = blockIdx.x;
    const int t = threadIdx.x;
    const float* Xb = X + (size_t)b * T_ * F_;

    for (int idx = t; idx < T_*F_; idx += 256) ((float*)Xs)[idx] = Xb[idx];
    if (t < H_) Vs[t] = V[t];
    __syncthreads();

    // xw = X@W, xu = X@U : thread = (h, row-half), 16 rows each
    {
        const int h = t & 127, half = t >> 7;
        float aw[16], au[16];
        #pragma unroll
        for (int r = 0; r < 16; r++) { aw[r] = 0.f; au[r] = 0.f; }
        for (int f = 0; f < F_; f++) {
            const float wv = W[f*H_ + h];
            const float uv = U[f*H_ + h];
            #pragma unroll
            for (int r = 0; r < 16; r++) {
                const float xv = Xs[half*16 + r][f];
                aw[r] += xv * wv;
                au[r] += xv * uv;
            }
        }
        #pragma unroll
        for (int r = 0; r < 16; r++) {
            xw[half*16 + r][h] = aw[r];
            xu[half*16 + r][h] = au[r];
        }
    }
    __syncthreads();

    // scores[i][j] = sum_h tanh(xw[i][h]+xu[j][h]) * V[h]
    {
        const int i = t >> 3;
        const int j0 = (t & 7) * 4;
        float s0 = 0.f, s1 = 0.f, s2 = 0.f, s3 = 0.f;
        for (int h = 0; h < H_; h++) {
            const float xwv = xw[i][h];
            const float vv  = Vs[h];
            s0 += tanhf(xwv + xu[j0+0][h]) * vv;
            s1 += tanhf(xwv + xu[j0+1][h]) * vv;
            s2 += tanhf(xwv + xu[j0+2][h]) * vv;
            s3 += tanhf(xwv + xu[j0+3][h]) * vv;
        }
        sc[i][j0+0] = s0; sc[i][j0+1] = s1; sc[i][j0+2] = s2; sc[i][j0+3] = s3;
    }
    __syncthreads();

    // softmax over j (full row incl diag), then zero diagonal (mask AFTER softmax)
    if (t < T_) {
        float m = -1e30f;
        #pragma unroll
        for (int j = 0; j < T_; j++) m = fmaxf(m, sc[t][j]);
        float sum = 0.f;
        #pragma unroll
        for (int j = 0; j < T_; j++) sum += expf(sc[t][j] - m);
        const float inv = 1.f / sum;
        #pragma unroll
        for (int j = 0; j < T_; j++) {
            const float a = expf(sc[t][j] - m) * inv;
            sc[t][j] = (j == t) ? 0.f : a;
        }
    }
    __syncthreads();

    // c = (alpha*mask) @ X ; feat = [X, c]
    for (int idx = t; idx < T_*F_; idx += 256) {
        const int row = idx >> 7, f = idx & 127;
        float acc = 0.f;
        #pragma unroll
        for (int j = 0; j < T_; j++) acc += sc[row][j] * Xs[j][f];
        float* fr = feat + ((size_t)(b*T_ + row)) * 256;
        fr[f]       = Xs[row][f];
        fr[128 + f] = acc;
    }
}

// ------- K2: fused conv + GEMM1 partials. tile 128x128, K-chunked -------
__global__ __launch_bounds__(256) void k_gemm1(
    const float* __restrict__ feat, const float* __restrict__ cw,
    const float* __restrict__ cb, const float* __restrict__ w1,
    float* __restrict__ partial, int KC_)
{
    __shared__ float As[32][136];   // [kk][m], padded
    __shared__ float Ws[32][128];   // [kk][n]
    __shared__ float cwS[256];
    __shared__ float cbS[64];

    const int t  = threadIdx.x;
    const int mt = blockIdx.x & 1;
    const int nt = blockIdx.x >> 1;
    const int kt = blockIdx.y;

    cwS[t] = cw[t];
    if (t < 64) cbS[t] = cb[t];
    __syncthreads();

    const int m0 = (t & 15) * 8;
    const int n0 = (t >> 4) * 8;
    float acc[8][8];
    #pragma unroll
    for (int q = 0; q < 8; q++)
        #pragma unroll
        for (int r = 0; r < 8; r++) acc[q][r] = 0.f;

    long k0   = (long)kt * KC_;
    long kend = k0 + KC_;
    if (kend > KFLAT) kend = KFLAT;

    const int kkA = t & 31, mgA = t >> 5;     // A staging role
    const int nnW = t & 127, kgW = t >> 7;    // W staging role

    for (long kb = k0; kb < kend; kb += 32) {
        // ---- stage A (conv on the fly): 32kk x 128m
        {
            const long k = kb + kkA;
            const bool kv = (k < kend);
            float c0=0.f,c1=0.f,c2=0.f,c3=0.f,bb=0.f;
            int y=0, x=0;
            if (kv) {
                const int ki = (int)k;
                const int n = ki / 7905;
                const int r = ki - n*7905;
                y = r / 255;
                x = r - y*255;
                c0 = cwS[n*4+0]; c1 = cwS[n*4+1];
                c2 = cwS[n*4+2]; c3 = cwS[n*4+3];
                bb = cbS[n];
            }
            #pragma unroll
            for (int s = 0; s < 16; s++) {
                const int m = mgA*16 + s;
                float a = 0.f;
                if (kv) {
                    const int bi = mt*128 + m;
                    const float* fp = feat + ((size_t)bi*T_ + y)*256 + x;
                    const float v = fp[0]*c0 + fp[1]*c1 + fp[256]*c2 + fp[257]*c3 + bb;
                    a = fmaxf(v, 0.f);
                }
                As[kkA][m] = a;
            }
        }
        // ---- stage W1: 32kk x 128n
        #pragma unroll
        for (int s = 0; s < 16; s++) {
            const int kk = kgW*16 + s;
            const long k = kb + kk;
            Ws[kk][nnW] = (k < kend) ? w1[(size_t)k*N1 + nt*128 + nnW] : 0.f;
        }
        __syncthreads();

        // ---- 128x128x32 fp32 FMA, 8x8 per thread
        #pragma unroll 8
        for (int kk = 0; kk < 32; kk++) {
            float a[8], w[8];
            *(float4*)&a[0] = *(const float4*)&As[kk][m0];
            *(float4*)&a[4] = *(const float4*)&As[kk][m0+4];
            *(float4*)&w[0] = *(const float4*)&Ws[kk][n0];
            *(float4*)&w[4] = *(const float4*)&Ws[kk][n0+4];
            #pragma unroll
            for (int q = 0; q < 8; q++)
                #pragma unroll
                for (int r = 0; r < 8; r++)
                    acc[q][r] += a[q] * w[r];
        }
        __syncthreads();
    }

    float* pp = partial + (size_t)kt * (256*N1);
    #pragma unroll
    for (int q = 0; q < 8; q++) {
        const int row = mt*128 + m0 + q;
        *(float4*)&pp[(size_t)row*N1 + nt*128 + n0    ] = *(float4*)&acc[q][0];
        *(float4*)&pp[(size_t)row*N1 + nt*128 + n0 + 4] = *(float4*)&acc[q][4];
    }
}

// ------- K3: reduce partials + b1/relu + h@w2 relu + @w3 + b3 -------
__global__ __launch_bounds__(256) void k_head(
    const float* __restrict__ partial, int KT_,
    const float* __restrict__ b1, const float* __restrict__ w2,
    const float* __restrict__ b2, const float* __restrict__ w3,
    const float* __restrict__ b3, float* __restrict__ out)
{
    __shared__ float h1s[256];
    __shared__ float h2s[32];
    const int b = blockIdx.x, t = threadIdx.x;

    float s = b1[t];
    for (int kt = 0; kt < KT_; kt++)
        s += partial[(size_t)kt*(256*N1) + (size_t)b*N1 + t];
    h1s[t] = fmaxf(s, 0.f);
    __syncthreads();

    if (t < 32) {
        float s2 = b2[t];
        for (int i = 0; i < 256; i++) s2 += h1s[i] * w2[i*32 + t];
        h2s[t] = fmaxf(s2, 0.f);
    }
    __syncthreads();

    if (t < 2) {
        float s3 = b3[t];
        #pragma unroll
        for (int i = 0; i < 32; i++) s3 += h2s[i] * w3[i*2 + t];
        out[b*2 + t] = s3;
    }
}

extern "C" void kernel_launch(void* const* d_in, const int* in_sizes, int n_in,
                              void* d_out, int out_size, void* d_ws, size_t ws_size,
                              hipStream_t stream) {
    const float* X    = (const float*)d_in[0];
    const float* attW = (const float*)d_in[1];
    const float* attU = (const float*)d_in[2];
    const float* attV = (const float*)d_in[3];
    const float* cw   = (const float*)d_in[4];
    const float* cb   = (const float*)d_in[5];
    const float* w1   = (const float*)d_in[6];
    const float* b1   = (const float*)d_in[7];
    const float* w2   = (const float*)d_in[8];
    const float* b2   = (const float*)d_in[9];
    const float* w3   = (const float*)d_in[10];
    const float* b3   = (const float*)d_in[11];
    float* out = (float*)d_out;

    const size_t feat_bytes = (size_t)B_ * T_ * 256 * sizeof(float);  // 8 MB
    float* feat    = (float*)d_ws;
    float* partial = (float*)((char*)d_ws + feat_bytes);

    // K-split count sized to available workspace (deterministic per run)
    long avail = (long)ws_size - (long)feat_bytes;
    int KT = (int)(avail / (256L * N1 * sizeof(float)));
    if (KT > 124) KT = 124;
    if (KT < 1)  KT = 1;
    const int KC = (KFLAT + KT - 1) / KT;

    k_attn <<<dim3(B_),     dim3(256), 0, stream>>>(X, attW, attU, attV, feat);
    k_gemm1<<<dim3(4, KT),  dim3(256), 0, stream>>>(feat, cw, cb, w1, partial, KC);
    k_head <<<dim3(B_),     dim3(256), 0, stream>>>(partial, KT, b1, w2, b2, w3, b3, out);
}

// Round 2
// 1843.552 us; speedup vs baseline: 1.0005x; 1.0005x over previous
//
#include <hip/hip_runtime.h>
#include <hip/hip_bf16.h>

#define B_ 256
#define T_ 32
#define F_ 128
#define H_ 128
#define NF 64
#define OH 31
#define OW 255
#define KFLAT (NF*OH*OW)   // 505920
#define N1 256

typedef __attribute__((ext_vector_type(8))) short bf16x8;
typedef __attribute__((ext_vector_type(4))) float f32x4;

__device__ __forceinline__ unsigned short f2bf_rne(float f) {
    unsigned int u = __float_as_uint(f);
    u += 0x7FFFu + ((u >> 16) & 1u);
    return (unsigned short)(u >> 16);
}

// ---------------- K1: attention -> feat (B,32,256) ----------------
__global__ __launch_bounds__(256) void k_attn(
    const float* __restrict__ X, const float* __restrict__ W,
    const float* __restrict__ U, const float* __restrict__ V,
    float* __restrict__ feat)
{
    __shared__ float Xs[T_][F_];
    __shared__ float xw[T_][H_];
    __shared__ float xu[T_][H_];
    __shared__ float sc[T_][T_];
    __shared__ float Vs[H_];

    const int b = blockIdx.x;
    const int t = threadIdx.x;
    const float* Xb = X + (size_t)b * T_ * F_;

    for (int idx = t; idx < T_*F_; idx += 256) ((float*)Xs)[idx] = Xb[idx];
    if (t < H_) Vs[t] = V[t];
    __syncthreads();

    {
        const int h = t & 127, half = t >> 7;
        float aw[16], au[16];
        #pragma unroll
        for (int r = 0; r < 16; r++) { aw[r] = 0.f; au[r] = 0.f; }
        for (int f = 0; f < F_; f++) {
            const float wv = W[f*H_ + h];
            const float uv = U[f*H_ + h];
            #pragma unroll
            for (int r = 0; r < 16; r++) {
                const float xv = Xs[half*16 + r][f];
                aw[r] += xv * wv;
                au[r] += xv * uv;
            }
        }
        #pragma unroll
        for (int r = 0; r < 16; r++) {
            xw[half*16 + r][h] = aw[r];
            xu[half*16 + r][h] = au[r];
        }
    }
    __syncthreads();

    {
        const int i = t >> 3;
        const int j0 = (t & 7) * 4;
        float s0 = 0.f, s1 = 0.f, s2 = 0.f, s3 = 0.f;
        for (int h = 0; h < H_; h++) {
            const float xwv = xw[i][h];
            const float vv  = Vs[h];
            s0 += tanhf(xwv + xu[j0+0][h]) * vv;
            s1 += tanhf(xwv + xu[j0+1][h]) * vv;
            s2 += tanhf(xwv + xu[j0+2][h]) * vv;
            s3 += tanhf(xwv + xu[j0+3][h]) * vv;
        }
        sc[i][j0+0] = s0; sc[i][j0+1] = s1; sc[i][j0+2] = s2; sc[i][j0+3] = s3;
    }
    __syncthreads();

    if (t < T_) {
        float m = -1e30f;
        #pragma unroll
        for (int j = 0; j < T_; j++) m = fmaxf(m, sc[t][j]);
        float sum = 0.f;
        #pragma unroll
        for (int j = 0; j < T_; j++) sum += expf(sc[t][j] - m);
        const float inv = 1.f / sum;
        #pragma unroll
        for (int j = 0; j < T_; j++) {
            const float a = expf(sc[t][j] - m) * inv;
            sc[t][j] = (j == t) ? 0.f : a;
        }
    }
    __syncthreads();

    for (int idx = t; idx < T_*F_; idx += 256) {
        const int row = idx >> 7, f = idx & 127;
        float acc = 0.f;
        #pragma unroll
        for (int j = 0; j < T_; j++) acc += sc[row][j] * Xs[j][f];
        float* fr = feat + ((size_t)(b*T_ + row)) * 256;
        fr[f]       = Xs[row][f];
        fr[128 + f] = acc;
    }
}

// ------- K2: fused conv + MFMA GEMM1 partials. tile 128x128, K-split -------
__global__ __launch_bounds__(256) void k_gemm1(
    const float* __restrict__ feat, const float* __restrict__ cw,
    const float* __restrict__ cb, const float* __restrict__ w1,
    float* __restrict__ partial, int KC_)
{
    // LDS rows padded to 40 shorts (80B pitch) -> ~conflict-free ds_read_b128
    __shared__ unsigned short As[128][40];   // A tile, [m][k]
    __shared__ unsigned short Wh[128][40];   // w1 hi, [n][k] (transposed)
    __shared__ unsigned short Wl[128][40];   // w1 lo, [n][k]
    __shared__ float cwS[256];
    __shared__ float cbS[64];

    const int t  = threadIdx.x;
    const int mt = blockIdx.x & 1;
    const int nt = blockIdx.x >> 1;
    const int kt = blockIdx.y;

    cwS[t] = cw[t];
    if (t < 64) cbS[t] = cb[t];

    const int lane = t & 63;
    const int wid  = t >> 6;
    const int wm = (wid & 1) * 64;   // wave m-offset in tile
    const int wn = (wid >> 1) * 64;  // wave n-offset in tile
    const int fr = lane & 15;
    const int fq = lane >> 4;

    f32x4 acc[4][4];
    #pragma unroll
    for (int i = 0; i < 4; i++)
        #pragma unroll
        for (int j = 0; j < 4; j++)
            acc[i][j] = (f32x4){0.f, 0.f, 0.f, 0.f};

    int k0   = kt * KC_;
    int kend = k0 + KC_;
    if (kend > KFLAT) kend = KFLAT;

    const int ms = t & 127;        // staging row (m for A, n for W)
    const int kh = (t >> 7) * 16;  // staging k-half

    const int bi = mt*128 + ms;    // batch row for A staging

    __syncthreads();   // cwS/cbS ready

    for (int kb = k0; kb < kend; kb += 32) {
        // ---- stage A: conv on the fly, 16 k's for row ms ----
        {
            unsigned int apk[8];
            #pragma unroll
            for (int i = 0; i < 16; i++) {
                const int k = kb + kh + i;
                float v = 0.f;
                if (k < kend) {
                    const int n = k / 7905;
                    const int r = k - n*7905;
                    const int y = r / 255;
                    const int x = r - y*255;
                    const float* fp = feat + ((size_t)(bi*T_ + y))*256 + x;
                    const float4 cc = *(const float4*)&cwS[n*4];
                    v = fp[0]*cc.x + fp[1]*cc.y + fp[256]*cc.z + fp[257]*cc.w + cbS[n];
                    v = fmaxf(v, 0.f);
                }
                const unsigned short bf = f2bf_rne(v);
                if (i & 1) apk[i>>1] |= ((unsigned int)bf) << 16;
                else       apk[i>>1]  = bf;
            }
            *(uint4*)&As[ms][kh]     = *(uint4*)&apk[0];
            *(uint4*)&As[ms][kh + 8] = *(uint4*)&apk[4];
        }
        // ---- stage W1 hi/lo (transposed to [n][k]) ----
        {
            unsigned int hpk[8], lpk[8];
            const float* wp = w1 + (size_t)(kb + kh)*N1 + nt*128 + ms;
            #pragma unroll
            for (int i = 0; i < 16; i++) {
                const int k = kb + kh + i;
                float w = 0.f;
                if (k < kend) w = wp[(size_t)i*N1];
                const unsigned int u  = __float_as_uint(w);
                const unsigned int hi = u & 0xFFFF0000u;
                const float lo = w - __uint_as_float(hi);
                const unsigned short hb = (unsigned short)(u >> 16);
                const unsigned short lb = f2bf_rne(lo);
                if (i & 1) { hpk[i>>1] |= ((unsigned int)hb) << 16; lpk[i>>1] |= ((unsigned int)lb) << 16; }
                else       { hpk[i>>1]  = hb;                       lpk[i>>1]  = lb; }
            }
            *(uint4*)&Wh[ms][kh]     = *(uint4*)&hpk[0];
            *(uint4*)&Wh[ms][kh + 8] = *(uint4*)&hpk[4];
            *(uint4*)&Wl[ms][kh]     = *(uint4*)&lpk[0];
            *(uint4*)&Wl[ms][kh + 8] = *(uint4*)&lpk[4];
        }
        __syncthreads();

        // ---- MFMA: wave computes 64x64, K=32 (hi + lo) ----
        {
            bf16x8 af[4];
            #pragma unroll
            for (int mg = 0; mg < 4; mg++)
                af[mg] = *(const bf16x8*)&As[wm + mg*16 + fr][fq*8];
            #pragma unroll
            for (int ng = 0; ng < 4; ng++) {
                const bf16x8 bh = *(const bf16x8*)&Wh[wn + ng*16 + fr][fq*8];
                const bf16x8 bl = *(const bf16x8*)&Wl[wn + ng*16 + fr][fq*8];
                #pragma unroll
                for (int mg = 0; mg < 4; mg++) {
                    acc[mg][ng] = __builtin_amdgcn_mfma_f32_16x16x32_bf16(af[mg], bh, acc[mg][ng], 0, 0, 0);
                    acc[mg][ng] = __builtin_amdgcn_mfma_f32_16x16x32_bf16(af[mg], bl, acc[mg][ng], 0, 0, 0);
                }
            }
        }
        __syncthreads();
    }

    // ---- write fp32 partial tile ----
    float* pp = partial + (size_t)kt*(256*N1) + (size_t)(mt*128)*N1 + nt*128;
    #pragma unroll
    for (int mg = 0; mg < 4; mg++)
        #pragma unroll
        for (int ng = 0; ng < 4; ng++) {
            const int col = wn + ng*16 + fr;
            #pragma unroll
            for (int r = 0; r < 4; r++) {
                const int row = wm + mg*16 + fq*4 + r;
                pp[(size_t)row*N1 + col] = acc[mg][ng][r];
            }
        }
}

// ------- K3: reduce partials + b1/relu + h@w2 relu + @w3 + b3 -------
__global__ __launch_bounds__(256) void k_head(
    const float* __restrict__ partial, int KT_,
    const float* __restrict__ b1, const float* __restrict__ w2,
    const float* __restrict__ b2, const float* __restrict__ w3,
    const float* __restrict__ b3, float* __restrict__ out)
{
    __shared__ float h1s[256];
    __shared__ float h2s[32];
    const int b = blockIdx.x, t = threadIdx.x;

    float s = b1[t];
    for (int kt = 0; kt < KT_; kt++)
        s += partial[(size_t)kt*(256*N1) + (size_t)b*N1 + t];
    h1s[t] = fmaxf(s, 0.f);
    __syncthreads();

    if (t < 32) {
        float s2 = b2[t];
        for (int i = 0; i < 256; i++) s2 += h1s[i] * w2[i*32 + t];
        h2s[t] = fmaxf(s2, 0.f);
    }
    __syncthreads();

    if (t < 2) {
        float s3 = b3[t];
        #pragma unroll
        for (int i = 0; i < 32; i++) s3 += h2s[i] * w3[i*2 + t];
        out[b*2 + t] = s3;
    }
}

extern "C" void kernel_launch(void* const* d_in, const int* in_sizes, int n_in,
                              void* d_out, int out_size, void* d_ws, size_t ws_size,
                              hipStream_t stream) {
    const float* X    = (const float*)d_in[0];
    const float* attW = (const float*)d_in[1];
    const float* attU = (const float*)d_in[2];
    const float* attV = (const float*)d_in[3];
    const float* cw   = (const float*)d_in[4];
    const float* cb   = (const float*)d_in[5];
    const float* w1   = (const float*)d_in[6];
    const float* b1   = (const float*)d_in[7];
    const float* w2   = (const float*)d_in[8];
    const float* b2   = (const float*)d_in[9];
    const float* w3   = (const float*)d_in[10];
    const float* b3   = (const float*)d_in[11];
    float* out = (float*)d_out;

    const size_t feat_bytes = (size_t)B_ * T_ * 256 * sizeof(float);  // 8 MB
    float* feat    = (float*)d_ws;
    float* partial = (float*)((char*)d_ws + feat_bytes);

    long avail = (long)ws_size - (long)feat_bytes;
    int KT = (int)(avail / (256L * N1 * sizeof(float)));
    if (KT > 124) KT = 124;
    if (KT < 1)  KT = 1;
    const int KC = (KFLAT + KT - 1) / KT;

    k_attn <<<dim3(B_),     dim3(256), 0, stream>>>(X, attW, attU, attV, feat);
    k_gemm1<<<dim3(4, KT),  dim3(256), 0, stream>>>(feat, cw, cb, w1, partial, KC);
    k_head <<<dim3(B_),     dim3(256), 0, stream>>>(partial, KT, b1, w2, b2, w3, b3, out);
}

// Round 3
// 356.867 us; speedup vs baseline: 5.1686x; 5.1659x over previous
//
#include <hip/hip_runtime.h>
#include <hip/hip_bf16.h>

#define B_ 256
#define T_ 32
#define F_ 128
#define H_ 128
#define NF 64
#define OH 31
#define OW 255
#define POS_TOTAL (OH*OW)      // 7905
#define KFLAT (NF*OH*OW)       // 505920
#define N1 256

typedef __attribute__((ext_vector_type(8))) short bf16x8;
typedef __attribute__((ext_vector_type(4))) float f32x4;

__device__ __forceinline__ unsigned short f2bf_rne(float f) {
    unsigned int u = __float_as_uint(f);
    u += 0x7FFFu + ((u >> 16) & 1u);
    return (unsigned short)(u >> 16);
}

// ---------------- K1: attention -> featT [y=32][xcol=256][b=256] ----------------
__global__ __launch_bounds__(256) void k_attn(
    const float* __restrict__ X, const float* __restrict__ W,
    const float* __restrict__ U, const float* __restrict__ V,
    float* __restrict__ featT)
{
    __shared__ float Xs[T_][F_];
    __shared__ float xw[T_][H_];
    __shared__ float xu[T_][H_];
    __shared__ float sc[T_][T_];
    __shared__ float Vs[H_];

    const int b = blockIdx.x;
    const int t = threadIdx.x;
    const float* Xb = X + (size_t)b * T_ * F_;

    for (int idx = t; idx < T_*F_; idx += 256) ((float*)Xs)[idx] = Xb[idx];
    if (t < H_) Vs[t] = V[t];
    __syncthreads();

    {
        const int h = t & 127, half = t >> 7;
        float aw[16], au[16];
        #pragma unroll
        for (int r = 0; r < 16; r++) { aw[r] = 0.f; au[r] = 0.f; }
        for (int f = 0; f < F_; f++) {
            const float wv = W[f*H_ + h];
            const float uv = U[f*H_ + h];
            #pragma unroll
            for (int r = 0; r < 16; r++) {
                const float xv = Xs[half*16 + r][f];
                aw[r] += xv * wv;
                au[r] += xv * uv;
            }
        }
        #pragma unroll
        for (int r = 0; r < 16; r++) {
            xw[half*16 + r][h] = aw[r];
            xu[half*16 + r][h] = au[r];
        }
    }
    __syncthreads();

    {
        const int i = t >> 3;
        const int j0 = (t & 7) * 4;
        float s0 = 0.f, s1 = 0.f, s2 = 0.f, s3 = 0.f;
        for (int h = 0; h < H_; h++) {
            const float xwv = xw[i][h];
            const float vv  = Vs[h];
            s0 += tanhf(xwv + xu[j0+0][h]) * vv;
            s1 += tanhf(xwv + xu[j0+1][h]) * vv;
            s2 += tanhf(xwv + xu[j0+2][h]) * vv;
            s3 += tanhf(xwv + xu[j0+3][h]) * vv;
        }
        sc[i][j0+0] = s0; sc[i][j0+1] = s1; sc[i][j0+2] = s2; sc[i][j0+3] = s3;
    }
    __syncthreads();

    if (t < T_) {
        float m = -1e30f;
        #pragma unroll
        for (int j = 0; j < T_; j++) m = fmaxf(m, sc[t][j]);
        float sum = 0.f;
        #pragma unroll
        for (int j = 0; j < T_; j++) sum += expf(sc[t][j] - m);
        const float inv = 1.f / sum;
        #pragma unroll
        for (int j = 0; j < T_; j++) {
            const float a = expf(sc[t][j] - m) * inv;
            sc[t][j] = (j == t) ? 0.f : a;
        }
    }
    __syncthreads();

    // featT[(y*256 + xc)*256 + b]; xc = f for X part, 128+f for context part
    for (int idx = t; idx < T_*F_; idx += 256) {
        const int row = idx >> 7, f = idx & 127;
        float acc = 0.f;
        #pragma unroll
        for (int j = 0; j < T_; j++) acc += sc[row][j] * Xs[j][f];
        featT[((size_t)(row*256 + f))*256 + b]       = Xs[row][f];
        featT[((size_t)(row*256 + 128 + f))*256 + b] = acc;
    }
}

// ------- K2: fused conv + MFMA GEMM1, permuted K (pos-major, f-inner) -------
// Block: M=256 (all batch) x N=128 (nt half). K-step = 1 position x 64 filters.
// LDS: double-buffered, XOR-swizzled 16B blocks, 128 KiB total.
__global__ __launch_bounds__(512, 2) void k_gemm1(
    const float* __restrict__ featT, const float* __restrict__ cw,
    const float* __restrict__ cb, const float* __restrict__ w1,
    float* __restrict__ partial, int PPB)
{
    __shared__ unsigned short As[2][256*64];   // 64 KiB  [m=256][k=64]
    __shared__ unsigned short Wh[2][128*64];   // 32 KiB  [n=128][k=64]
    __shared__ unsigned short Wl[2][128*64];   // 32 KiB

    const int t  = threadIdx.x;
    const int nt = blockIdx.x;
    const int kt = blockIdx.y;

    // --- A staging role: 4 rows x 8 filters per thread ---
    const int ar = t & 63;          // base row (lane-coalesced)
    const int ag = t >> 6;          // filter group 0..7 -> f = ag*8+i
    float4 cwR[8];
    float  cbR[8];
    #pragma unroll
    for (int i = 0; i < 8; i++) {
        cwR[i] = *(const float4*)&cw[(ag*8 + i) * 4];
        cbR[i] = cb[ag*8 + i];
    }

    // --- W staging role: 1 n-row x 16 filters per thread ---
    const int wrow = t & 127;
    const int fW   = (t >> 7) * 16;     // 0,16,32,48

    // --- MFMA role: 8 waves as 4m x 2n, wave tile 64x64 ---
    const int lane = t & 63;
    const int wid  = t >> 6;
    const int wm   = (wid & 3) * 64;
    const int wn   = (wid >> 2) * 64;
    const int fr   = lane & 15;
    const int fq   = lane >> 4;

    f32x4 acc[4][4];
    #pragma unroll
    for (int i = 0; i < 4; i++)
        #pragma unroll
        for (int j = 0; j < 4; j++)
            acc[i][j] = (f32x4){0.f, 0.f, 0.f, 0.f};

    const int pos0   = kt * PPB;
    int pend = pos0 + PPB; if (pend > POS_TOTAL) pend = POS_TOTAL;
    const int nsteps = pend - pos0;

    float pv[4][4];    // 4 rows x 4 taps
    float wvv[16];     // 16 w1 values

#define DO_LOADS(POS)                                                          \
    {                                                                          \
        const int y_ = (POS) / 255;                                            \
        const int x_ = (POS) - y_ * 255;                                       \
        const float* fT_ = featT + ((size_t)(y_ * 256 + x_)) * 256;            \
        _Pragma("unroll")                                                      \
        for (int q = 0; q < 4; q++) {                                          \
            const int row_ = ar + 64 * q;                                      \
            pv[q][0] = fT_[row_];                                              \
            pv[q][1] = fT_[256 + row_];                                        \
            pv[q][2] = fT_[65536 + row_];                                      \
            pv[q][3] = fT_[65536 + 256 + row_];                                \
        }                                                                      \
        const float* wp_ = w1 + (size_t)(fW * POS_TOTAL + (POS)) * N1          \
                              + nt * 128 + wrow;                               \
        _Pragma("unroll")                                                      \
        for (int i = 0; i < 16; i++)                                           \
            wvv[i] = wp_[(size_t)i * POS_TOTAL * N1];                          \
    }

#define DO_WRITE(BUF)                                                          \
    {                                                                          \
        _Pragma("unroll")                                                      \
        for (int q = 0; q < 4; q++) {                                          \
            const int row_ = ar + 64 * q;                                      \
            unsigned int pk_[4];                                               \
            _Pragma("unroll")                                                  \
            for (int i = 0; i < 8; i++) {                                      \
                float v_ = pv[q][0]*cwR[i].x + pv[q][1]*cwR[i].y               \
                         + pv[q][2]*cwR[i].z + pv[q][3]*cwR[i].w + cbR[i];     \
                v_ = fmaxf(v_, 0.f);                                           \
                const unsigned short us_ = f2bf_rne(v_);                       \
                if (i & 1) pk_[i>>1] |= (unsigned int)us_ << 16;               \
                else       pk_[i>>1]  = us_;                                   \
            }                                                                  \
            const int blk_ = ag ^ (row_ & 7);                                  \
            *(uint4*)&As[BUF][row_*64 + blk_*8] = *(uint4*)&pk_[0];            \
        }                                                                      \
        unsigned int hpk_[8], lpk_[8];                                         \
        _Pragma("unroll")                                                      \
        for (int i = 0; i < 16; i++) {                                         \
            const unsigned int u_ = __float_as_uint(wvv[i]);                   \
            const float hif_ = __uint_as_float(u_ & 0xFFFF0000u);              \
            const unsigned short hb_ = (unsigned short)(u_ >> 16);             \
            const unsigned short lb_ = f2bf_rne(wvv[i] - hif_);                \
            if (i & 1) { hpk_[i>>1] |= (unsigned int)hb_ << 16;                \
                         lpk_[i>>1] |= (unsigned int)lb_ << 16; }              \
            else       { hpk_[i>>1]  = hb_; lpk_[i>>1]  = lb_; }               \
        }                                                                      \
        const int b0_ = ((fW >> 3) + 0) ^ (wrow & 7);                          \
        const int b1_ = ((fW >> 3) + 1) ^ (wrow & 7);                          \
        *(uint4*)&Wh[BUF][wrow*64 + b0_*8] = *(uint4*)&hpk_[0];                \
        *(uint4*)&Wh[BUF][wrow*64 + b1_*8] = *(uint4*)&hpk_[4];                \
        *(uint4*)&Wl[BUF][wrow*64 + b0_*8] = *(uint4*)&lpk_[0];                \
        *(uint4*)&Wl[BUF][wrow*64 + b1_*8] = *(uint4*)&lpk_[4];                \
    }

#define DO_MFMA(BUF)                                                           \
    {                                                                          \
        _Pragma("unroll")                                                      \
        for (int c = 0; c < 2; c++) {                                          \
            const int kb_ = (c*4 + fq) ^ (fr & 7);                             \
            bf16x8 af_[4];                                                     \
            _Pragma("unroll")                                                  \
            for (int mg = 0; mg < 4; mg++)                                     \
                af_[mg] = *(const bf16x8*)&As[BUF][(wm + mg*16 + fr)*64 + kb_*8];\
            _Pragma("unroll")                                                  \
            for (int ng = 0; ng < 4; ng++) {                                   \
                const int nr_ = wn + ng*16 + fr;                               \
                const bf16x8 bh_ = *(const bf16x8*)&Wh[BUF][nr_*64 + kb_*8];   \
                const bf16x8 bl_ = *(const bf16x8*)&Wl[BUF][nr_*64 + kb_*8];   \
                _Pragma("unroll")                                              \
                for (int mg = 0; mg < 4; mg++) {                               \
                    acc[mg][ng] = __builtin_amdgcn_mfma_f32_16x16x32_bf16(     \
                        af_[mg], bh_, acc[mg][ng], 0, 0, 0);                   \
                    acc[mg][ng] = __builtin_amdgcn_mfma_f32_16x16x32_bf16(     \
                        af_[mg], bl_, acc[mg][ng], 0, 0, 0);                   \
                }                                                              \
            }                                                                  \
        }                                                                      \
    }

    if (nsteps > 0) {
        DO_LOADS(pos0);
        DO_WRITE(0);
    }
    __syncthreads();

    for (int s = 0; s < nsteps; s++) {
        const int cur = s & 1;
        if (s + 1 < nsteps) DO_LOADS(pos0 + s + 1);   // issue early (T14)
        DO_MFMA(cur);
        if (s + 1 < nsteps) DO_WRITE(cur ^ 1);        // convert+write late
        __syncthreads();
    }

    // ---- write fp32 partial tile [kt][m=256][n slice] ----
    float* pp = partial + (size_t)kt * (B_ * N1) + (size_t)nt * 128;
    #pragma unroll
    for (int mg = 0; mg < 4; mg++)
        #pragma unroll
        for (int ng = 0; ng < 4; ng++) {
            const int col = wn + ng*16 + fr;
            #pragma unroll
            for (int r = 0; r < 4; r++) {
                const int row = wm + mg*16 + fq*4 + r;
                pp[(size_t)row*N1 + col] = acc[mg][ng][r];
            }
        }
#undef DO_LOADS
#undef DO_WRITE
#undef DO_MFMA
}

// ------- K3: reduce partials + b1/relu + h@w2 relu + @w3 + b3 -------
__global__ __launch_bounds__(256) void k_head(
    const float* __restrict__ partial, int KT_,
    const float* __restrict__ b1, const float* __restrict__ w2,
    const float* __restrict__ b2, const float* __restrict__ w3,
    const float* __restrict__ b3, float* __restrict__ out)
{
    __shared__ float h1s[256];
    __shared__ float h2s[32];
    const int b = blockIdx.x, t = threadIdx.x;

    float s = b1[t];
    for (int kt = 0; kt < KT_; kt++)
        s += partial[(size_t)kt*(256*N1) + (size_t)b*N1 + t];
    h1s[t] = fmaxf(s, 0.f);
    __syncthreads();

    if (t < 32) {
        float s2 = b2[t];
        for (int i = 0; i < 256; i++) s2 += h1s[i] * w2[i*32 + t];
        h2s[t] = fmaxf(s2, 0.f);
    }
    __syncthreads();

    if (t < 2) {
        float s3 = b3[t];
        #pragma unroll
        for (int i = 0; i < 32; i++) s3 += h2s[i] * w3[i*2 + t];
        out[b*2 + t] = s3;
    }
}

extern "C" void kernel_launch(void* const* d_in, const int* in_sizes, int n_in,
                              void* d_out, int out_size, void* d_ws, size_t ws_size,
                              hipStream_t stream) {
    const float* X    = (const float*)d_in[0];
    const float* attW = (const float*)d_in[1];
    const float* attU = (const float*)d_in[2];
    const float* attV = (const float*)d_in[3];
    const float* cw   = (const float*)d_in[4];
    const float* cb   = (const float*)d_in[5];
    const float* w1   = (const float*)d_in[6];
    const float* b1   = (const float*)d_in[7];
    const float* w2   = (const float*)d_in[8];
    const float* b2   = (const float*)d_in[9];
    const float* w3   = (const float*)d_in[10];
    const float* b3   = (const float*)d_in[11];
    float* out = (float*)d_out;

    const size_t featT_bytes = (size_t)T_ * 256 * 256 * sizeof(float);  // 8 MB
    float* featT   = (float*)d_ws;
    float* partial = (float*)((char*)d_ws + featT_bytes);

    long avail = (long)ws_size - (long)featT_bytes;
    int KT = (int)(avail / (256L * N1 * sizeof(float)));
    if (KT > 124) KT = 124;
    if (KT < 1)  KT = 1;
    const int PPB = (POS_TOTAL + KT - 1) / KT;   // positions per block (64 @ KT=124)

    k_attn <<<dim3(B_),      dim3(256), 0, stream>>>(X, attW, attU, attV, featT);
    k_gemm1<<<dim3(2, KT),   dim3(512), 0, stream>>>(featT, cw, cb, w1, partial, PPB);
    k_head <<<dim3(B_),      dim3(256), 0, stream>>>(partial, KT, b1, w2, b2, w3, b3, out);
}

// Round 4
// 324.525 us; speedup vs baseline: 5.6837x; 1.0997x over previous
//
#include <hip/hip_runtime.h>
#include <hip/hip_bf16.h>

#define B_ 256
#define T_ 32
#define F_ 128
#define H_ 128
#define NF 64
#define OH 31
#define OW 255
#define POS_TOTAL (OH*OW)      // 7905
#define N1 256
#define KT 248                 // K-slice blocks
#define NPB 4                  // pos-blocks (of 8 pos) per block
#define NSTEPS (NPB*8)         // 32 K-steps of 64

typedef __attribute__((ext_vector_type(8))) short bf16x8;
typedef __attribute__((ext_vector_type(4))) float f32x4;

__device__ __forceinline__ unsigned short f2bf_rne(float f) {
    unsigned int u = __float_as_uint(f);
    u += 0x7FFFu + ((u >> 16) & 1u);
    return (unsigned short)(u >> 16);
}

// ---------------- K1: attention -> featL [b=256][rc=8192] ----------------
__global__ __launch_bounds__(256) void k_attn(
    const float* __restrict__ X, const float* __restrict__ W,
    const float* __restrict__ U, const float* __restrict__ V,
    float* __restrict__ featL)
{
    __shared__ float Xs[T_][F_];
    __shared__ float xw[T_][H_];
    __shared__ float xu[T_][H_];
    __shared__ float sc[T_][T_];
    __shared__ float Vs[H_];

    const int b = blockIdx.x;
    const int t = threadIdx.x;
    const float* Xb = X + (size_t)b * T_ * F_;

    for (int idx = t; idx < T_*F_; idx += 256) ((float*)Xs)[idx] = Xb[idx];
    if (t < H_) Vs[t] = V[t];
    __syncthreads();

    {
        const int h = t & 127, half = t >> 7;
        float aw[16], au[16];
        #pragma unroll
        for (int r = 0; r < 16; r++) { aw[r] = 0.f; au[r] = 0.f; }
        for (int f = 0; f < F_; f++) {
            const float wv = W[f*H_ + h];
            const float uv = U[f*H_ + h];
            #pragma unroll
            for (int r = 0; r < 16; r++) {
                const float xv = Xs[half*16 + r][f];
                aw[r] += xv * wv;
                au[r] += xv * uv;
            }
        }
        #pragma unroll
        for (int r = 0; r < 16; r++) {
            xw[half*16 + r][h] = aw[r];
            xu[half*16 + r][h] = au[r];
        }
    }
    __syncthreads();

    {
        const int i = t >> 3;
        const int j0 = (t & 7) * 4;
        float s0 = 0.f, s1 = 0.f, s2 = 0.f, s3 = 0.f;
        for (int h = 0; h < H_; h++) {
            const float xwv = xw[i][h];
            const float vv  = Vs[h];
            s0 += tanhf(xwv + xu[j0+0][h]) * vv;
            s1 += tanhf(xwv + xu[j0+1][h]) * vv;
            s2 += tanhf(xwv + xu[j0+2][h]) * vv;
            s3 += tanhf(xwv + xu[j0+3][h]) * vv;
        }
        sc[i][j0+0] = s0; sc[i][j0+1] = s1; sc[i][j0+2] = s2; sc[i][j0+3] = s3;
    }
    __syncthreads();

    if (t < T_) {
        float m = -1e30f;
        #pragma unroll
        for (int j = 0; j < T_; j++) m = fmaxf(m, sc[t][j]);
        float sum = 0.f;
        #pragma unroll
        for (int j = 0; j < T_; j++) sum += expf(sc[t][j] - m);
        const float inv = 1.f / sum;
        #pragma unroll
        for (int j = 0; j < T_; j++) {
            const float a = expf(sc[t][j] - m) * inv;
            sc[t][j] = (j == t) ? 0.f : a;
        }
    }
    __syncthreads();

    // featL[b][row*256 + xc] : coalesced stores (lanes along xc)
    for (int idx = t; idx < T_*F_; idx += 256) {
        const int row = idx >> 7, f = idx & 127;
        float acc = 0.f;
        #pragma unroll
        for (int j = 0; j < T_; j++) acc += sc[row][j] * Xs[j][f];
        float* fr = featL + (size_t)b*8192 + row*256;
        fr[f]       = Xs[row][f];
        fr[128 + f] = acc;
    }
}

// -------- K1b: transpose featL[b][rc] -> featT[rc][b], LDS-tiled --------
__global__ __launch_bounds__(256) void k_tr(
    const float* __restrict__ src, float* __restrict__ dst)
{
    __shared__ float tile[32][33];
    const int rc0 = blockIdx.x * 32;     // 8192/32 = 256
    const int b0  = blockIdx.y * 32;     // 256/32  = 8
    const int tx = threadIdx.x & 31;
    const int ty = threadIdx.x >> 5;     // 0..7
    #pragma unroll
    for (int r = 0; r < 32; r += 8)
        tile[ty + r][tx] = src[(size_t)(b0 + ty + r)*8192 + rc0 + tx];
    __syncthreads();
    #pragma unroll
    for (int r = 0; r < 32; r += 8)
        dst[(size_t)(rc0 + ty + r)*256 + b0 + tx] = tile[tx][ty + r];
}

// ------- K2: fused conv + MFMA GEMM1. K-step = 8 filters x 8 consecutive pos -------
// Block: 256x256 output tile, K-slice = 32 pos (NPB pos-blocks). w1 reads contiguous.
__global__ __launch_bounds__(512, 2) void k_gemm1(
    const float* __restrict__ featT, const float* __restrict__ cw,
    const float* __restrict__ cb, const float* __restrict__ w1,
    float* __restrict__ partial)
{
    __shared__ unsigned short As[2][256*64];   // 64 KiB  [m][k] swizzled
    __shared__ unsigned short Ws[2][256*64];   // 64 KiB  [n][k] swizzled
    __shared__ float cwL[256];
    __shared__ float cbL[64];

    const int t  = threadIdx.x;
    const int kt = blockIdx.x;

    if (t < 256) cwL[t] = cw[t];
    if (t < 64)  cbL[t] = cb[t];

    const int rn  = t & 255;     // A-row (batch) / W-col (n)
    const int fq2 = t >> 8;      // 0/1: which 32-k half this thread stages
    const int rsw = rn & 7;      // swizzle key

    // MFMA role: 8 waves = 2(m) x 4(n); wave tile 128x64
    const int lane = t & 63, wid = t >> 6;
    const int wm = (wid >> 2) * 128;
    const int wn = (wid & 3) * 64;
    const int fr = lane & 15, fq = lane >> 4;

    f32x4 acc[8][4];
    #pragma unroll
    for (int i = 0; i < 8; i++)
        #pragma unroll
        for (int j = 0; j < 4; j++)
            acc[i][j] = (f32x4){0.f, 0.f, 0.f, 0.f};

    float patch[4][8];   // 4 taps x 8 pos (per pos-block, reused over 8 fg steps)
    float wvv[4][8];     // w1 values for next step: 4 fl x 8 pi

    const int pb0 = kt * NPB;

#define PATCH_LOADS(PB)                                                        \
    {                                                                          \
        const int pbase_ = (PB) * 8;                                           \
        _Pragma("unroll")                                                      \
        for (int pi = 0; pi < 8; pi++) {                                       \
            int pos_ = pbase_ + pi;                                            \
            if (pos_ > POS_TOTAL-1) pos_ = POS_TOTAL-1;                        \
            const int y_ = pos_ / 255;                                         \
            const int x_ = pos_ - y_*255;                                      \
            const float* fp_ = featT + ((size_t)(y_*256 + x_))*256 + rn;       \
            patch[0][pi] = fp_[0];                                             \
            patch[1][pi] = fp_[256];                                           \
            patch[2][pi] = fp_[65536];                                         \
            patch[3][pi] = fp_[65536 + 256];                                   \
        }                                                                      \
    }

#define W_LOADS(SG)                                                            \
    {                                                                          \
        const int pbase_ = (pb0 + ((SG) >> 3)) * 8;                            \
        const int fg_ = (SG) & 7;                                              \
        _Pragma("unroll")                                                      \
        for (int fl = 0; fl < 4; fl++) {                                       \
            const int f_ = fg_*8 + fq2*4 + fl;                                 \
            _Pragma("unroll")                                                  \
            for (int pi = 0; pi < 8; pi++) {                                   \
                int pos_ = pbase_ + pi;                                        \
                if (pos_ > POS_TOTAL-1) pos_ = POS_TOTAL-1;                    \
                wvv[fl][pi] = w1[(size_t)(f_*POS_TOTAL + pos_)*N1 + rn];       \
            }                                                                  \
        }                                                                      \
    }

#define STAGE_WRITE(BUF, SG)                                                   \
    {                                                                          \
        const int pbase_ = (pb0 + ((SG) >> 3)) * 8;                            \
        const int fg_ = (SG) & 7;                                              \
        _Pragma("unroll")                                                      \
        for (int fl = 0; fl < 4; fl++) {                                       \
            const int f_ = fg_*8 + fq2*4 + fl;                                 \
            const float4 cc_ = *(const float4*)&cwL[f_*4];                     \
            const float cbv_ = cbL[f_];                                        \
            unsigned int apk_[4], wpk_[4];                                     \
            _Pragma("unroll")                                                  \
            for (int pi = 0; pi < 8; pi++) {                                   \
                float v_ = patch[0][pi]*cc_.x + patch[1][pi]*cc_.y             \
                         + patch[2][pi]*cc_.z + patch[3][pi]*cc_.w + cbv_;     \
                v_ = (pbase_ + pi < POS_TOTAL) ? fmaxf(v_, 0.f) : 0.f;         \
                const unsigned short ab_ = f2bf_rne(v_);                       \
                const unsigned short wb_ = f2bf_rne(wvv[fl][pi]);              \
                if (pi & 1) { apk_[pi>>1] |= (unsigned int)ab_ << 16;          \
                              wpk_[pi>>1] |= (unsigned int)wb_ << 16; }        \
                else        { apk_[pi>>1]  = ab_; wpk_[pi>>1]  = wb_; }        \
            }                                                                  \
            const int blk_ = (fq2*4 + fl) ^ rsw;                               \
            *(uint4*)&As[BUF][rn*64 + blk_*8] = *(uint4*)&apk_[0];             \
            *(uint4*)&Ws[BUF][rn*64 + blk_*8] = *(uint4*)&wpk_[0];             \
        }                                                                      \
    }

#define DO_MFMA(BUF)                                                           \
    {                                                                          \
        _Pragma("unroll")                                                      \
        for (int c = 0; c < 2; c++) {                                          \
            const int swz_ = ((c*4 + fq) ^ (fr & 7)) * 8;                      \
            bf16x8 af_[8], bf_[4];                                             \
            _Pragma("unroll")                                                  \
            for (int mg = 0; mg < 8; mg++)                                     \
                af_[mg] = *(const bf16x8*)&As[BUF][(wm + mg*16 + fr)*64 + swz_];\
            _Pragma("unroll")                                                  \
            for (int ng = 0; ng < 4; ng++)                                     \
                bf_[ng] = *(const bf16x8*)&Ws[BUF][(wn + ng*16 + fr)*64 + swz_];\
            _Pragma("unroll")                                                  \
            for (int mg = 0; mg < 8; mg++)                                     \
                _Pragma("unroll")                                              \
                for (int ng = 0; ng < 4; ng++)                                 \
                    acc[mg][ng] = __builtin_amdgcn_mfma_f32_16x16x32_bf16(     \
                        af_[mg], bf_[ng], acc[mg][ng], 0, 0, 0);               \
        }                                                                      \
    }

    PATCH_LOADS(pb0);
    W_LOADS(0);
    __syncthreads();            // cwL/cbL visible
    STAGE_WRITE(0, 0);
    __syncthreads();

    #pragma unroll 1
    for (int S = 0; S < NSTEPS; S++) {
        const int cur = S & 1;
        if (S + 1 < NSTEPS) {
            if (((S + 1) & 7) == 0) PATCH_LOADS(pb0 + ((S + 1) >> 3));
            W_LOADS(S + 1);
        }
        DO_MFMA(cur);
        if (S + 1 < NSTEPS) STAGE_WRITE(cur ^ 1, S + 1);
        __syncthreads();
    }

    // ---- write fp32 partial tile ----
    float* pp = partial + (size_t)kt * (256*256);
    #pragma unroll
    for (int mg = 0; mg < 8; mg++)
        #pragma unroll
        for (int ng = 0; ng < 4; ng++) {
            const int col = wn + ng*16 + fr;
            #pragma unroll
            for (int j = 0; j < 4; j++) {
                const int row = wm + mg*16 + fq*4 + j;
                pp[(size_t)row*256 + col] = acc[mg][ng][j];
            }
        }
#undef PATCH_LOADS
#undef W_LOADS
#undef STAGE_WRITE
#undef DO_MFMA
}

// ------- K3: reduce partials + b1/relu + h@w2 relu + @w3 + b3 -------
__global__ __launch_bounds__(256) void k_head(
    const float* __restrict__ partial, int KT_,
    const float* __restrict__ b1, const float* __restrict__ w2,
    const float* __restrict__ b2, const float* __restrict__ w3,
    const float* __restrict__ b3, float* __restrict__ out)
{
    __shared__ float h1s[256];
    __shared__ float h2s[32];
    const int b = blockIdx.x, t = threadIdx.x;

    float s = b1[t];
    for (int kt = 0; kt < KT_; kt++)
        s += partial[(size_t)kt*(256*N1) + (size_t)b*N1 + t];
    h1s[t] = fmaxf(s, 0.f);
    __syncthreads();

    if (t < 32) {
        float s2 = b2[t];
        for (int i = 0; i < 256; i++) s2 += h1s[i] * w2[i*32 + t];
        h2s[t] = fmaxf(s2, 0.f);
    }
    __syncthreads();

    if (t < 2) {
        float s3 = b3[t];
        #pragma unroll
        for (int i = 0; i < 32; i++) s3 += h2s[i] * w3[i*2 + t];
        out[b*2 + t] = s3;
    }
}

extern "C" void kernel_launch(void* const* d_in, const int* in_sizes, int n_in,
                              void* d_out, int out_size, void* d_ws, size_t ws_size,
                              hipStream_t stream) {
    const float* X    = (const float*)d_in[0];
    const float* attW = (const float*)d_in[1];
    const float* attU = (const float*)d_in[2];
    const float* attV = (const float*)d_in[3];
    const float* cw   = (const float*)d_in[4];
    const float* cb   = (const float*)d_in[5];
    const float* w1   = (const float*)d_in[6];
    const float* b1   = (const float*)d_in[7];
    const float* w2   = (const float*)d_in[8];
    const float* b2   = (const float*)d_in[9];
    const float* w3   = (const float*)d_in[10];
    const float* b3   = (const float*)d_in[11];
    float* out = (float*)d_out;

    float* featL   = (float*)d_ws;                                   //  8 MB
    float* featT   = (float*)((char*)d_ws + (8u<<20));               //  8 MB
    float* partial = (float*)((char*)d_ws + (16u<<20));              // 62 MB

    k_attn <<<dim3(B_),       dim3(256), 0, stream>>>(X, attW, attU, attV, featL);
    k_tr   <<<dim3(256, 8),   dim3(256), 0, stream>>>(featL, featT);
    k_gemm1<<<dim3(KT),       dim3(512), 0, stream>>>(featT, cw, cb, w1, partial);
    k_head <<<dim3(B_),       dim3(256), 0, stream>>>(partial, KT, b1, w2, b2, w3, b3, out);
}

// Round 5
// 324.255 us; speedup vs baseline: 5.6884x; 1.0008x over previous
//
#include <hip/hip_runtime.h>
#include <hip/hip_bf16.h>

#define B_ 256
#define T_ 32
#define F_ 128
#define H_ 128
#define NF 64
#define OH 31
#define OW 255
#define POS_TOTAL (OH*OW)      // 7905
#define N1 256
#define KT 248                 // K-slice blocks
#define NSTEPS 64              // 64 steps of K=32 per block (4 pos-blocks x 16 fg)

typedef __attribute__((ext_vector_type(8))) short bf16x8;
typedef __attribute__((ext_vector_type(4))) float f32x4;

__device__ __forceinline__ unsigned short f2bf_rne(float f) {
    unsigned int u = __float_as_uint(f);
    u += 0x7FFFu + ((u >> 16) & 1u);
    return (unsigned short)(u >> 16);
}

// ---------------- K1: attention -> featL [b=256][rc=8192] ----------------
__global__ __launch_bounds__(256) void k_attn(
    const float* __restrict__ X, const float* __restrict__ W,
    const float* __restrict__ U, const float* __restrict__ V,
    float* __restrict__ featL)
{
    __shared__ float Xs[T_][F_];
    __shared__ float xw[T_][H_];
    __shared__ float xu[T_][H_];
    __shared__ float sc[T_][T_];
    __shared__ float Vs[H_];

    const int b = blockIdx.x;
    const int t = threadIdx.x;
    const float* Xb = X + (size_t)b * T_ * F_;

    for (int idx = t; idx < T_*F_; idx += 256) ((float*)Xs)[idx] = Xb[idx];
    if (t < H_) Vs[t] = V[t];
    __syncthreads();

    {
        const int h = t & 127, half = t >> 7;
        float aw[16], au[16];
        #pragma unroll
        for (int r = 0; r < 16; r++) { aw[r] = 0.f; au[r] = 0.f; }
        for (int f = 0; f < F_; f++) {
            const float wv = W[f*H_ + h];
            const float uv = U[f*H_ + h];
            #pragma unroll
            for (int r = 0; r < 16; r++) {
                const float xv = Xs[half*16 + r][f];
                aw[r] += xv * wv;
                au[r] += xv * uv;
            }
        }
        #pragma unroll
        for (int r = 0; r < 16; r++) {
            xw[half*16 + r][h] = aw[r];
            xu[half*16 + r][h] = au[r];
        }
    }
    __syncthreads();

    {
        const int i = t >> 3;
        const int j0 = (t & 7) * 4;
        float s0 = 0.f, s1 = 0.f, s2 = 0.f, s3 = 0.f;
        for (int h = 0; h < H_; h++) {
            const float xwv = xw[i][h];
            const float vv  = Vs[h];
            s0 += tanhf(xwv + xu[j0+0][h]) * vv;
            s1 += tanhf(xwv + xu[j0+1][h]) * vv;
            s2 += tanhf(xwv + xu[j0+2][h]) * vv;
            s3 += tanhf(xwv + xu[j0+3][h]) * vv;
        }
        sc[i][j0+0] = s0; sc[i][j0+1] = s1; sc[i][j0+2] = s2; sc[i][j0+3] = s3;
    }
    __syncthreads();

    if (t < T_) {
        float m = -1e30f;
        #pragma unroll
        for (int j = 0; j < T_; j++) m = fmaxf(m, sc[t][j]);
        float sum = 0.f;
        #pragma unroll
        for (int j = 0; j < T_; j++) sum += expf(sc[t][j] - m);
        const float inv = 1.f / sum;
        #pragma unroll
        for (int j = 0; j < T_; j++) {
            const float a = expf(sc[t][j] - m) * inv;
            sc[t][j] = (j == t) ? 0.f : a;
        }
    }
    __syncthreads();

    for (int idx = t; idx < T_*F_; idx += 256) {
        const int row = idx >> 7, f = idx & 127;
        float acc = 0.f;
        #pragma unroll
        for (int j = 0; j < T_; j++) acc += sc[row][j] * Xs[j][f];
        float* fr = featL + (size_t)b*8192 + row*256;
        fr[f]       = Xs[row][f];
        fr[128 + f] = acc;
    }
}

// -------- K1b: transpose featL[b][rc] -> featT[rc][b], LDS-tiled --------
__global__ __launch_bounds__(256) void k_tr(
    const float* __restrict__ src, float* __restrict__ dst)
{
    __shared__ float tile[32][33];
    const int rc0 = blockIdx.x * 32;
    const int b0  = blockIdx.y * 32;
    const int tx = threadIdx.x & 31;
    const int ty = threadIdx.x >> 5;
    #pragma unroll
    for (int r = 0; r < 32; r += 8)
        tile[ty + r][tx] = src[(size_t)(b0 + ty + r)*8192 + rc0 + tx];
    __syncthreads();
    #pragma unroll
    for (int r = 0; r < 32; r += 8)
        dst[(size_t)(rc0 + ty + r)*256 + b0 + tx] = tile[tx][ty + r];
}

// ------- K2: fused conv + MFMA GEMM1. K-step = 4 filters x 8 consecutive pos -------
// Block: 256x256 tile, 64 steps (4 pos-blocks x 16 filter-groups).
// LDS layout k-block-major [blk][row][8] -> conflict-free b128 r/w, no swizzle.
__global__ __launch_bounds__(512, 2) void k_gemm1(
    const float* __restrict__ featT, const float* __restrict__ cw,
    const float* __restrict__ cb, const float* __restrict__ w1,
    float* __restrict__ partial)
{
    __shared__ unsigned short As[2*4*256*8];   // 32 KiB
    __shared__ unsigned short Ws[2*4*256*8];   // 32 KiB
    __shared__ float cwL[256];
    __shared__ float cbL[64];

    const int t  = threadIdx.x;
    const int kt = blockIdx.x;

    if (t < 256) cwL[t] = cw[t];
    if (t < 64)  cbL[t] = cb[t];

    const int rn  = t & 255;     // A-row (batch) / W-col (n)
    const int fq2 = t >> 8;      // 0/1: filter-pair within step

    // MFMA role: 8 waves = 2(m) x 4(n); wave tile 128x64
    const int lane = t & 63, wid = t >> 6;
    const int wm = (wid >> 2) * 128;
    const int wn = (wid & 3) * 64;
    const int fr = lane & 15, fq = lane >> 4;

    f32x4 acc[8][4];
    #pragma unroll
    for (int i = 0; i < 8; i++)
        #pragma unroll
        for (int j = 0; j < 4; j++)
            acc[i][j] = (f32x4){0.f, 0.f, 0.f, 0.f};

    float patch[4][8];   // 4 taps x 8 pos, reused over 16 fg steps
    float wvv[2][8];     // next step's w1: 2 filters x 8 pos

    const int pb0 = kt * 4;      // pos-block base (8 pos each)

#define PATCH_LOADS(PB)                                                        \
    {                                                                          \
        const int pbase_ = (PB) * 8;                                           \
        _Pragma("unroll")                                                      \
        for (int pi = 0; pi < 8; pi++) {                                       \
            int pos_ = pbase_ + pi;                                            \
            if (pos_ > POS_TOTAL-1) pos_ = POS_TOTAL-1;                        \
            const int y_ = pos_ / 255;                                         \
            const int x_ = pos_ - y_*255;                                      \
            const float* fp_ = featT + ((size_t)(y_*256 + x_))*256 + rn;       \
            patch[0][pi] = fp_[0];                                             \
            patch[1][pi] = fp_[256];                                           \
            patch[2][pi] = fp_[65536];                                         \
            patch[3][pi] = fp_[65536 + 256];                                   \
        }                                                                      \
    }

#define W_LOADS(SG)                                                            \
    {                                                                          \
        const int fg_ = (SG) & 15;                                             \
        const int pbase_ = (pb0 + ((SG) >> 4)) * 8;                            \
        _Pragma("unroll")                                                      \
        for (int j = 0; j < 2; j++) {                                          \
            const int f_ = fg_*4 + fq2*2 + j;                                  \
            _Pragma("unroll")                                                  \
            for (int pi = 0; pi < 8; pi++) {                                   \
                int pos_ = pbase_ + pi;                                        \
                if (pos_ > POS_TOTAL-1) pos_ = POS_TOTAL-1;                    \
                wvv[j][pi] = w1[(size_t)(f_*POS_TOTAL + pos_)*N1 + rn];        \
            }                                                                  \
        }                                                                      \
    }

#define STAGE_WRITE(BUF, SG)                                                   \
    {                                                                          \
        const int fg_ = (SG) & 15;                                             \
        const int pbase_ = (pb0 + ((SG) >> 4)) * 8;                            \
        _Pragma("unroll")                                                      \
        for (int j = 0; j < 2; j++) {                                          \
            const int f_ = fg_*4 + fq2*2 + j;                                  \
            const float4 cc_ = *(const float4*)&cwL[f_*4];                     \
            const float cbv_ = cbL[f_];                                        \
            unsigned int apk_[4], wpk_[4];                                     \
            _Pragma("unroll")                                                  \
            for (int pi = 0; pi < 8; pi++) {                                   \
                float v_ = patch[0][pi]*cc_.x + patch[1][pi]*cc_.y             \
                         + patch[2][pi]*cc_.z + patch[3][pi]*cc_.w + cbv_;     \
                v_ = (pbase_ + pi < POS_TOTAL) ? fmaxf(v_, 0.f) : 0.f;         \
                const unsigned short ab_ = f2bf_rne(v_);                       \
                const unsigned short wb_ = f2bf_rne(wvv[j][pi]);               \
                if (pi & 1) { apk_[pi>>1] |= (unsigned int)ab_ << 16;          \
                              wpk_[pi>>1] |= (unsigned int)wb_ << 16; }        \
                else        { apk_[pi>>1]  = ab_; wpk_[pi>>1]  = wb_; }        \
            }                                                                  \
            const int blk_ = fq2*2 + j;                                        \
            *(uint4*)&As[(((BUF)*4 + blk_)*256 + rn)*8] = *(uint4*)&apk_[0];   \
            *(uint4*)&Ws[(((BUF)*4 + blk_)*256 + rn)*8] = *(uint4*)&wpk_[0];   \
        }                                                                      \
    }

#define DO_MFMA(BUF)                                                           \
    {                                                                          \
        bf16x8 af_[8], bf_[4];                                                 \
        _Pragma("unroll")                                                      \
        for (int mg = 0; mg < 8; mg++)                                         \
            af_[mg] = *(const bf16x8*)&As[(((BUF)*4 + fq)*256 + wm+mg*16+fr)*8];\
        _Pragma("unroll")                                                      \
        for (int ng = 0; ng < 4; ng++)                                         \
            bf_[ng] = *(const bf16x8*)&Ws[(((BUF)*4 + fq)*256 + wn+ng*16+fr)*8];\
        _Pragma("unroll")                                                      \
        for (int mg = 0; mg < 8; mg++)                                         \
            _Pragma("unroll")                                                  \
            for (int ng = 0; ng < 4; ng++)                                     \
                acc[mg][ng] = __builtin_amdgcn_mfma_f32_16x16x32_bf16(         \
                    af_[mg], bf_[ng], acc[mg][ng], 0, 0, 0);                   \
    }

    PATCH_LOADS(pb0);
    W_LOADS(0);
    __syncthreads();            // cwL/cbL visible
    STAGE_WRITE(0, 0);
    __syncthreads();

    #pragma unroll 1
    for (int S = 0; S < NSTEPS; S++) {
        const int cur = S & 1;
        if (S + 1 < NSTEPS) {
            if (((S + 1) & 15) == 0) PATCH_LOADS(pb0 + ((S + 1) >> 4));
            W_LOADS(S + 1);
        }
        DO_MFMA(cur);
        if (S + 1 < NSTEPS) STAGE_WRITE(cur ^ 1, S + 1);
        __syncthreads();
    }

    // ---- write fp32 partial tile ----
    float* pp = partial + (size_t)kt * (256*256);
    #pragma unroll
    for (int mg = 0; mg < 8; mg++)
        #pragma unroll
        for (int ng = 0; ng < 4; ng++) {
            const int col = wn + ng*16 + fr;
            #pragma unroll
            for (int j = 0; j < 4; j++) {
                const int row = wm + mg*16 + fq*4 + j;
                pp[(size_t)row*256 + col] = acc[mg][ng][j];
            }
        }
#undef PATCH_LOADS
#undef W_LOADS
#undef STAGE_WRITE
#undef DO_MFMA
}

// ------- K3: reduce partials + b1/relu + h@w2 relu + @w3 + b3 -------
__global__ __launch_bounds__(256) void k_head(
    const float* __restrict__ partial, int KT_,
    const float* __restrict__ b1, const float* __restrict__ w2,
    const float* __restrict__ b2, const float* __restrict__ w3,
    const float* __restrict__ b3, float* __restrict__ out)
{
    __shared__ float h1s[256];
    __shared__ float h2s[32];
    const int b = blockIdx.x, t = threadIdx.x;

    float s = b1[t];
    for (int kt = 0; kt < KT_; kt++)
        s += partial[(size_t)kt*(256*N1) + (size_t)b*N1 + t];
    h1s[t] = fmaxf(s, 0.f);
    __syncthreads();

    if (t < 32) {
        float s2 = b2[t];
        for (int i = 0; i < 256; i++) s2 += h1s[i] * w2[i*32 + t];
        h2s[t] = fmaxf(s2, 0.f);
    }
    __syncthreads();

    if (t < 2) {
        float s3 = b3[t];
        #pragma unroll
        for (int i = 0; i < 32; i++) s3 += h2s[i] * w3[i*2 + t];
        out[b*2 + t] = s3;
    }
}

extern "C" void kernel_launch(void* const* d_in, const int* in_sizes, int n_in,
                              void* d_out, int out_size, void* d_ws, size_t ws_size,
                              hipStream_t stream) {
    const float* X    = (const float*)d_in[0];
    const float* attW = (const float*)d_in[1];
    const float* attU = (const float*)d_in[2];
    const float* attV = (const float*)d_in[3];
    const float* cw   = (const float*)d_in[4];
    const float* cb   = (const float*)d_in[5];
    const float* w1   = (const float*)d_in[6];
    const float* b1   = (const float*)d_in[7];
    const float* w2   = (const float*)d_in[8];
    const float* b2   = (const float*)d_in[9];
    const float* w3   = (const float*)d_in[10];
    const float* b3   = (const float*)d_in[11];
    float* out = (float*)d_out;

    float* featL   = (float*)d_ws;                                   //  8 MB
    float* featT   = (float*)((char*)d_ws + (8u<<20));               //  8 MB
    float* partial = (float*)((char*)d_ws + (16u<<20));              // 62 MB

    k_attn <<<dim3(B_),       dim3(256), 0, stream>>>(X, attW, attU, attV, featL);
    k_tr   <<<dim3(256, 8),   dim3(256), 0, stream>>>(featL, featT);
    k_gemm1<<<dim3(KT),       dim3(512), 0, stream>>>(featT, cw, cb, w1, partial);
    k_head <<<dim3(B_),       dim3(256), 0, stream>>>(partial, KT, b1, w2, b2, w3, b3, out);
}